// Round 4
// baseline (728.107 us; speedup 1.0000x reference)
//
#include <hip/hip_runtime.h>

#define N_FEAT 128
#define F1 16
#define FH 8             // feature half
#define F2 2
#define XPAD 132
#define NPB 512          // nodes per bucket (power of two)
#define NPB_SHIFT 9
#define BMAX 256         // max buckets -> supports N <= 131072
#define CHUNK 8192       // edges per binning block
#define APAD 9           // LDS acc stride per node (8 + 1 pad)

// ---------------- degree (global atomics) + bucket histogram (LDS -> global) ----------------
__global__ __launch_bounds__(256) void deghist_kernel(const int* __restrict__ col, int E,
        int* __restrict__ deg, int* __restrict__ bcnt) {
    __shared__ int hist[BMAX];
    int t = threadIdx.x;
    hist[t] = 0;
    __syncthreads();
    int e0 = (blockIdx.x * 256 + t) * 4;
    if (e0 + 3 < E) {
        int4 c = *(const int4*)(col + e0);
        atomicAdd(&deg[c.x], 1); atomicAdd(&hist[c.x >> NPB_SHIFT], 1);
        atomicAdd(&deg[c.y], 1); atomicAdd(&hist[c.y >> NPB_SHIFT], 1);
        atomicAdd(&deg[c.z], 1); atomicAdd(&hist[c.z >> NPB_SHIFT], 1);
        atomicAdd(&deg[c.w], 1); atomicAdd(&hist[c.w >> NPB_SHIFT], 1);
    } else {
        for (int e = e0; e < E; ++e) {
            int c = col[e];
            atomicAdd(&deg[c], 1); atomicAdd(&hist[c >> NPB_SHIFT], 1);
        }
    }
    __syncthreads();
    if (hist[t]) atomicAdd(&bcnt[t], hist[t]);
}

__global__ void dinv_kernel(const int* __restrict__ deg, float* __restrict__ dinv, int N) {
    int i = blockIdx.x * blockDim.x + threadIdx.x;
    if (i < N) dinv[i] = rsqrtf((float)(deg[i] + 1));  // +1 self loop
}

// ---------------- exclusive scan of bucket counts (single block) ----------------
__global__ __launch_bounds__(256) void bscan_kernel(const int* __restrict__ bcnt,
        int* __restrict__ bstart, int* __restrict__ gcur, int E, int nbuck) {
    __shared__ int s[BMAX];
    int t = threadIdx.x;
    int v = (t < nbuck) ? bcnt[t] : 0;
    s[t] = v;
    __syncthreads();
    for (int off = 1; off < BMAX; off <<= 1) {
        int a = (t >= off) ? s[t - off] : 0;
        __syncthreads();
        s[t] += a;
        __syncthreads();
    }
    int excl = s[t] - v;
    if (t < nbuck) { bstart[t] = excl; gcur[t] = excl; }
    if (t == 0) bstart[nbuck] = E;
}

// ---------------- bin edges into buckets, LDS-staged for coalesced write-out ----------------
// ebin word = (src << NPB_SHIFT) | (dst & (NPB-1)), grouped by bucket = dst >> NPB_SHIFT
__global__ __launch_bounds__(256) void bin_kernel(const int* __restrict__ rowi,
        const int* __restrict__ coli, int* __restrict__ gcur,
        int* __restrict__ ebin, int E) {
    __shared__ int stage[CHUNK];
    __shared__ unsigned char sbkt[CHUNK];
    __shared__ int cnt[BMAX];
    __shared__ int pos[BMAX];
    __shared__ int runb[BMAX];
    int t = threadIdx.x;
    int base = blockIdx.x * CHUNK;
    int nval = E - base; if (nval > CHUNK) nval = CHUNK;
    cnt[t] = 0;
    __syncthreads();

    int cbuf[32];
#pragma unroll
    for (int j = 0; j < 8; ++j) {
        int idx = base + ((j << 8) + t) * 4;
        if (idx + 3 < E) {
            int4 c4 = *(const int4*)(coli + idx);
            cbuf[j * 4 + 0] = c4.x; cbuf[j * 4 + 1] = c4.y;
            cbuf[j * 4 + 2] = c4.z; cbuf[j * 4 + 3] = c4.w;
        } else {
#pragma unroll
            for (int u = 0; u < 4; ++u) {
                int i2 = idx + u;
                cbuf[j * 4 + u] = (i2 < E) ? coli[i2] : -1;
            }
        }
    }
#pragma unroll
    for (int k = 0; k < 32; ++k)
        if (cbuf[k] >= 0) atomicAdd(&cnt[cbuf[k] >> NPB_SHIFT], 1);
    __syncthreads();

    // inclusive scan of cnt into pos
    pos[t] = cnt[t];
    __syncthreads();
    for (int off = 1; off < BMAX; off <<= 1) {
        int a = (t >= off) ? pos[t - off] : 0;
        __syncthreads();
        pos[t] += a;
        __syncthreads();
    }
    int myc = cnt[t];
    int excl = pos[t] - myc;
    if (myc > 0) {
        int g = atomicAdd(&gcur[t], myc);
        runb[t] = g - excl;   // final addr for LDS slot i of bucket t = runb[t] + i
    }
    __syncthreads();
    cnt[t] = excl;            // scatter cursor
    __syncthreads();

#pragma unroll
    for (int j = 0; j < 8; ++j) {
        int idx = base + ((j << 8) + t) * 4;
        int rr[4];
        if (idx + 3 < E) {
            int4 r4 = *(const int4*)(rowi + idx);
            rr[0] = r4.x; rr[1] = r4.y; rr[2] = r4.z; rr[3] = r4.w;
        } else {
#pragma unroll
            for (int u = 0; u < 4; ++u) {
                int i2 = idx + u;
                rr[u] = (i2 < E) ? rowi[i2] : 0;
            }
        }
#pragma unroll
        for (int u = 0; u < 4; ++u) {
            int c = cbuf[j * 4 + u];
            if (c >= 0) {
                int b = c >> NPB_SHIFT;
                int lp = atomicAdd(&cnt[b], 1);
                stage[lp] = (rr[u] << NPB_SHIFT) | (c & (NPB - 1));
                sbkt[lp] = (unsigned char)b;
            }
        }
    }
    __syncthreads();
    // bucket-sorted, lane-consecutive write-out
    for (int i = t; i < nval; i += 256)
        ebin[runb[sbkt[i]] + i] = stage[i];
}

// ---------------- layer-1 GEMM: hs{A,B}[r][f] = dinv[r] * sum_k x[r,k]*W1[k,f] ----------------
__global__ __launch_bounds__(256) void gemm1_kernel(
    const float* __restrict__ x, const float* __restrict__ W1,
    const float* __restrict__ dinv, float* __restrict__ hsA,
    float* __restrict__ hsB, int N) {
    __shared__ __align__(16) float wsT[F1][XPAD];   // wsT[f][k] = W1[k][f]
    __shared__ __align__(16) float xs[16][XPAD];
    int t = threadIdx.x;
    for (int i = t; i < N_FEAT * F1; i += 256) {
        int k = i >> 4, f = i & 15;
        wsT[f][k] = W1[i];
    }
    int row0 = blockIdx.x * 16;
    for (int i = t; i < 16 * (N_FEAT / 4); i += 256) {
        int r = i >> 5, k4 = i & 31;
        int row = row0 + r;
        float4 v = (row < N) ? ((const float4*)(x + (size_t)row * N_FEAT))[k4]
                             : make_float4(0.f, 0.f, 0.f, 0.f);
        *(float4*)&xs[r][k4 * 4] = v;
    }
    __syncthreads();
    int rr = t >> 4, f = t & 15;
    int row = row0 + rr;
    if (row >= N) return;
    float acc = 0.f;
#pragma unroll
    for (int k4 = 0; k4 < 32; ++k4) {
        float4 xv = *(const float4*)&xs[rr][k4 * 4];
        float4 wv = *(const float4*)&wsT[f][k4 * 4];
        acc += xv.x * wv.x + xv.y * wv.y + xv.z * wv.z + xv.w * wv.w;
    }
    float v = acc * dinv[row];
    if (f < FH) hsA[(size_t)row * FH + f] = v;
    else        hsB[(size_t)row * FH + (f - FH)] = v;
}

// ------- layer-1 aggregate, one feature-half, split-K slices of each bucket -------
// One edge per lane, 4-deep unroll for MLP. hsH is 3.2 MB -> per-XCD L2-resident.
__global__ __launch_bounds__(512) void agg1_part_kernel(const int* __restrict__ bstart,
        const int* __restrict__ ebin, const float* __restrict__ hsH,
        float* __restrict__ partH, int K) {
    __shared__ float acc[NPB * APAD];
    int t = threadIdx.x;
    int bid = blockIdx.x;
    int b = bid / K, slice = bid - b * K;
    for (int i = t; i < NPB * APAD; i += 512) acc[i] = 0.f;
    __syncthreads();
    int s = bstart[b], e = bstart[b + 1];
    int len = e - s;
    int per = (len + K - 1) / K;
    int s0 = s + slice * per;
    int e0 = s0 + per; if (e0 > e) e0 = e;
    const float4* h4 = (const float4*)hsH;
    for (int i = s0 + t; i < e0; i += 2048) {
        int w[4]; float4 va[4], vb[4];
#pragma unroll
        for (int u = 0; u < 4; ++u) {
            int idx = i + u * 512;
            w[u] = (idx < e0) ? ebin[idx] : -1;
        }
#pragma unroll
        for (int u = 0; u < 4; ++u) {
            if (w[u] >= 0) {
                size_t r = (size_t)(w[u] >> NPB_SHIFT) * 2;
                va[u] = h4[r]; vb[u] = h4[r + 1];
            }
        }
#pragma unroll
        for (int u = 0; u < 4; ++u) {
            if (w[u] >= 0) {
                float* a = &acc[(w[u] & (NPB - 1)) * APAD];
                atomicAdd(a + 0, va[u].x); atomicAdd(a + 1, va[u].y);
                atomicAdd(a + 2, va[u].z); atomicAdd(a + 3, va[u].w);
                atomicAdd(a + 4, vb[u].x); atomicAdd(a + 5, vb[u].y);
                atomicAdd(a + 6, vb[u].z); atomicAdd(a + 7, vb[u].w);
            }
        }
    }
    __syncthreads();
    // flush partial: [node][2 float4], contiguous per block
    float4* p4 = (float4*)(partH + (size_t)bid * (NPB * FH));
    for (int i = t; i < NPB * FH / 4; i += 512) {
        int n = i >> 1, h = i & 1;
        float* a = &acc[n * APAD + h * 4];
        p4[i] = make_float4(a[0], a[1], a[2], a[3]);
    }
}

// ------- layer-1 combine partials + self + bias + relu + W2 -> hs2 (2 lanes/node) -------
__global__ __launch_bounds__(256) void fuse1_kernel(const float* __restrict__ partA,
        const float* __restrict__ partB, const float* __restrict__ hsA,
        const float* __restrict__ hsB, const float* __restrict__ dinv,
        const float* __restrict__ b1, const float* __restrict__ W2,
        float* __restrict__ hs2, int N, int K) {
    int tid = blockIdx.x * 256 + threadIdx.x;
    int g = tid >> 1;
    int h = tid & 1;      // feature half
    if (g >= N) return;
    int b = g >> NPB_SHIFT, n = g & (NPB - 1);
    const float4* h4 = (const float4*)(h ? hsB : hsA);
    const float4* p4 = (const float4*)(h ? partB : partA);
    float4 a0 = h4[(size_t)g * 2 + 0];   // self loop
    float4 a1 = h4[(size_t)g * 2 + 1];
    for (int sl = 0; sl < K; ++sl) {
        const float4* pp = p4 + ((size_t)(b * K + sl)) * (NPB * 2) + n * 2;
        float4 q0 = pp[0], q1 = pp[1];
        a0.x += q0.x; a0.y += q0.y; a0.z += q0.z; a0.w += q0.w;
        a1.x += q1.x; a1.y += q1.y; a1.z += q1.z; a1.w += q1.w;
    }
    float di = dinv[g];
    int f0 = h * FH;
    float vv[8] = {a0.x, a0.y, a0.z, a0.w, a1.x, a1.y, a1.z, a1.w};
    float h0 = 0.f, h1 = 0.f;
#pragma unroll
    for (int u = 0; u < 8; ++u) {
        float o = fmaxf(di * vv[u] + b1[f0 + u], 0.f);
        h0 += o * W2[(f0 + u) * F2 + 0];
        h1 += o * W2[(f0 + u) * F2 + 1];
    }
    h0 += __shfl_xor(h0, 1);
    h1 += __shfl_xor(h1, 1);
    if (h == 0) *(float2*)&hs2[(size_t)g * 2] = make_float2(di * h0, di * h1);
}

// ------- layer-2 aggregate, split-K (hs2 = 800 KB, L2-resident) -------
__global__ __launch_bounds__(256) void agg2_part_kernel(const int* __restrict__ bstart,
        const int* __restrict__ ebin, const float* __restrict__ hs2,
        float* __restrict__ part2, int K) {
    __shared__ float acc[NPB * 3];
    int t = threadIdx.x;
    int bid = blockIdx.x;
    int b = bid / K, slice = bid - b * K;
    for (int i = t; i < NPB * 3; i += 256) acc[i] = 0.f;
    __syncthreads();
    int s = bstart[b], e = bstart[b + 1];
    int len = e - s;
    int per = (len + K - 1) / K;
    int s0 = s + slice * per;
    int e0 = s0 + per; if (e0 > e) e0 = e;
    for (int i = s0 + t; i < e0; i += 1024) {
        int w[4];
#pragma unroll
        for (int u = 0; u < 4; ++u) {
            int idx = i + u * 256;
            w[u] = (idx < e0) ? ebin[idx] : -1;
        }
#pragma unroll
        for (int u = 0; u < 4; ++u) {
            if (w[u] >= 0) {
                float2 hv = *(const float2*)&hs2[(size_t)(w[u] >> NPB_SHIFT) * 2];
                int cl = w[u] & (NPB - 1);
                atomicAdd(&acc[cl * 3 + 0], hv.x);
                atomicAdd(&acc[cl * 3 + 1], hv.y);
            }
        }
    }
    __syncthreads();
    float2* p2 = (float2*)(part2 + (size_t)bid * (NPB * F2));
    for (int i = t; i < NPB; i += 256)
        p2[i] = make_float2(acc[i * 3 + 0], acc[i * 3 + 1]);
}

// ------- layer-2 combine + finalize -------
__global__ void fuse2_kernel(const float* __restrict__ part2,
        const float* __restrict__ hs2, const float* __restrict__ dinv,
        const float* __restrict__ b2, float* __restrict__ out, int N, int K) {
    int gid = blockIdx.x * blockDim.x + threadIdx.x;
    if (gid >= N * F2) return;
    int g = gid >> 1, j = gid & 1;
    int b = g >> NPB_SHIFT, n = g & (NPB - 1);
    float acc = 0.f;
    size_t rbase = ((size_t)b * K * NPB + n) * 2 + j;
    for (int s = 0; s < K; ++s) acc += part2[rbase + (size_t)s * NPB * 2];
    out[gid] = dinv[g] * (acc + hs2[gid]) + b2[j];
}

extern "C" void kernel_launch(void* const* d_in, const int* in_sizes, int n_in,
                              void* d_out, int out_size, void* d_ws, size_t ws_size,
                              hipStream_t stream) {
    const float* x  = (const float*)d_in[0];
    const int*   ei = (const int*)d_in[1];
    const float* W1 = (const float*)d_in[2];
    const float* b1 = (const float*)d_in[3];
    const float* W2 = (const float*)d_in[4];
    const float* b2 = (const float*)d_in[5];
    int N = in_sizes[0] / N_FEAT;
    int E = in_sizes[1] / 2;
    const int* rowi = ei;        // edge_index[0] = src
    const int* coli = ei + E;    // edge_index[1] = dst
    float* out = (float*)d_out;

    int nbuck = (N + NPB - 1) >> NPB_SHIFT;   // 196 for N=100000 (<= BMAX)

    // workspace layout (4B units)
    size_t NP = ((size_t)N + 1023) & ~(size_t)1023;
    size_t EP = ((size_t)E + 1023) & ~(size_t)1023;
    int*   wsI    = (int*)d_ws;
    int*   deg    = wsI;                          // NP
    float* dinv   = (float*)(wsI + NP);           // NP
    int*   bcnt   = wsI + 2 * NP;                 // 512
    int*   bstart = wsI + 2 * NP + 512;           // 512
    int*   gcur   = wsI + 2 * NP + 1024;          // 512
    float* hsA    = (float*)(wsI + 2 * NP + 2048);// 8*NP
    float* hsB    = hsA + 8 * NP;                 // 8*NP
    float* hs2    = hsB + 8 * NP;                 // 2*NP
    int*   ebin   = (int*)(hs2 + 2 * NP);         // EP
    float* partA  = (float*)(ebin + EP);
    size_t base   = 2 * NP + 2048 + 18 * NP + EP; // 4B units used so far

    // pick largest K (<=4) whose partial buffers fit the workspace
    int K = 4;
    while (K > 1) {
        size_t need = base + (size_t)K * nbuck * (NPB * F1 + NPB * F2);
        if (need * 4 <= ws_size) break;
        K >>= 1;
    }
    float* partB = partA + (size_t)K * nbuck * NPB * FH;
    float* part2 = partB + (size_t)K * nbuck * NPB * FH;

    hipMemsetAsync(deg, 0, (size_t)N * sizeof(int), stream);
    hipMemsetAsync(bcnt, 0, BMAX * sizeof(int), stream);

    deghist_kernel<<<((E + 3) / 4 + 255) / 256, 256, 0, stream>>>(coli, E, deg, bcnt);
    dinv_kernel<<<(N + 255) / 256, 256, 0, stream>>>(deg, dinv, N);
    bscan_kernel<<<1, BMAX, 0, stream>>>(bcnt, bstart, gcur, E, nbuck);
    bin_kernel<<<(E + CHUNK - 1) / CHUNK, 256, 0, stream>>>(rowi, coli, gcur, ebin, E);
    gemm1_kernel<<<(N + 15) / 16, 256, 0, stream>>>(x, W1, dinv, hsA, hsB, N);

    // two sequential passes, each with a 3.2 MB (L2-resident) gather working set
    agg1_part_kernel<<<nbuck * K, 512, 0, stream>>>(bstart, ebin, hsA, partA, K);
    agg1_part_kernel<<<nbuck * K, 512, 0, stream>>>(bstart, ebin, hsB, partB, K);
    fuse1_kernel<<<(N * 2 + 255) / 256, 256, 0, stream>>>(
        partA, partB, hsA, hsB, dinv, b1, W2, hs2, N, K);

    agg2_part_kernel<<<nbuck * K, 256, 0, stream>>>(bstart, ebin, hs2, part2, K);
    fuse2_kernel<<<(N * 2 + 255) / 256, 256, 0, stream>>>(part2, hs2, dinv, b2, out, N, K);
}

// Round 6
// 569.794 us; speedup vs baseline: 1.2778x; 1.2778x over previous
//
#include <hip/hip_runtime.h>

#define N_FEAT 128
#define F1 16
#define FH 8             // feature half
#define F2 2
#define XPAD 132
#define NPB 512          // nodes per bucket (power of two)
#define NPB_SHIFT 9
#define BMAX 256         // max buckets -> supports N <= 131072
#define CHUNK 8192       // edges per binning block
#define APAD 9           // LDS acc stride per node (8 + 1 pad)
#define HBLK 1024        // blocks for histogram kernel

// ---- nontemporal helpers (builtin requires native/ext_vector types) ----
typedef int   ev_i4 __attribute__((ext_vector_type(4)));
typedef float ev_f4 __attribute__((ext_vector_type(4)));
typedef float ev_f2 __attribute__((ext_vector_type(2)));

__device__ __forceinline__ int4 nt_load_i4(const void* p) {
    ev_i4 v = __builtin_nontemporal_load((const ev_i4*)p);
    return make_int4(v.x, v.y, v.z, v.w);
}
__device__ __forceinline__ int nt_load_i(const int* p) {
    return __builtin_nontemporal_load(p);
}
__device__ __forceinline__ float4 nt_load_f4(const void* p) {
    ev_f4 v = __builtin_nontemporal_load((const ev_f4*)p);
    return make_float4(v.x, v.y, v.z, v.w);
}
__device__ __forceinline__ float nt_load_f(const float* p) {
    return __builtin_nontemporal_load(p);
}
__device__ __forceinline__ void nt_store_i(int v, int* p) {
    __builtin_nontemporal_store(v, p);
}
__device__ __forceinline__ void nt_store_f4(float a, float b, float c, float d, void* p) {
    ev_f4 v = {a, b, c, d};
    __builtin_nontemporal_store(v, (ev_f4*)p);
}
__device__ __forceinline__ void nt_store_f2(float a, float b, void* p) {
    ev_f2 v = {a, b};
    __builtin_nontemporal_store(v, (ev_f2*)p);
}

// ---------------- bucket histogram only (NO per-node atomics) ----------------
__global__ __launch_bounds__(256) void hist_kernel(const int* __restrict__ col, int E,
        int* __restrict__ bcnt) {
    __shared__ int hist[BMAX];
    int t = threadIdx.x;
    hist[t] = 0;
    __syncthreads();
    int nq = (E + 3) >> 2;
    for (int q = blockIdx.x * 256 + t; q < nq; q += HBLK * 256) {
        int e0 = q * 4;
        if (e0 + 3 < E) {
            int4 c = nt_load_i4(col + e0);
            atomicAdd(&hist[c.x >> NPB_SHIFT], 1);
            atomicAdd(&hist[c.y >> NPB_SHIFT], 1);
            atomicAdd(&hist[c.z >> NPB_SHIFT], 1);
            atomicAdd(&hist[c.w >> NPB_SHIFT], 1);
        } else {
            for (int e = e0; e < E; ++e) atomicAdd(&hist[col[e] >> NPB_SHIFT], 1);
        }
    }
    __syncthreads();
    if (hist[t]) atomicAdd(&bcnt[t], hist[t]);
}

// ---------------- exclusive scan of bucket counts (single block) ----------------
__global__ __launch_bounds__(256) void bscan_kernel(const int* __restrict__ bcnt,
        int* __restrict__ bstart, int* __restrict__ gcur, int E, int nbuck) {
    __shared__ int s[BMAX];
    int t = threadIdx.x;
    int v = (t < nbuck) ? bcnt[t] : 0;
    s[t] = v;
    __syncthreads();
    for (int off = 1; off < BMAX; off <<= 1) {
        int a = (t >= off) ? s[t - off] : 0;
        __syncthreads();
        s[t] += a;
        __syncthreads();
    }
    int excl = s[t] - v;
    if (t < nbuck) { bstart[t] = excl; gcur[t] = excl; }
    if (t == 0) bstart[nbuck] = E;
}

// ---------------- bin edges into buckets, LDS-staged for coalesced write-out ----------------
// ebin word = (src << NPB_SHIFT) | (dst & (NPB-1)), grouped by bucket = dst >> NPB_SHIFT
__global__ __launch_bounds__(256) void bin_kernel(const int* __restrict__ rowi,
        const int* __restrict__ coli, int* __restrict__ gcur,
        int* __restrict__ ebin, int E) {
    __shared__ int stage[CHUNK];
    __shared__ unsigned char sbkt[CHUNK];
    __shared__ int cnt[BMAX];
    __shared__ int pos[BMAX];
    __shared__ int runb[BMAX];
    int t = threadIdx.x;
    int base = blockIdx.x * CHUNK;
    int nval = E - base; if (nval > CHUNK) nval = CHUNK;
    cnt[t] = 0;
    __syncthreads();

    int cbuf[32];
#pragma unroll
    for (int j = 0; j < 8; ++j) {
        int idx = base + ((j << 8) + t) * 4;
        if (idx + 3 < E) {
            int4 c4 = nt_load_i4(coli + idx);
            cbuf[j * 4 + 0] = c4.x; cbuf[j * 4 + 1] = c4.y;
            cbuf[j * 4 + 2] = c4.z; cbuf[j * 4 + 3] = c4.w;
        } else {
#pragma unroll
            for (int u = 0; u < 4; ++u) {
                int i2 = idx + u;
                cbuf[j * 4 + u] = (i2 < E) ? coli[i2] : -1;
            }
        }
    }
#pragma unroll
    for (int k = 0; k < 32; ++k)
        if (cbuf[k] >= 0) atomicAdd(&cnt[cbuf[k] >> NPB_SHIFT], 1);
    __syncthreads();

    // inclusive scan of cnt into pos
    pos[t] = cnt[t];
    __syncthreads();
    for (int off = 1; off < BMAX; off <<= 1) {
        int a = (t >= off) ? pos[t - off] : 0;
        __syncthreads();
        pos[t] += a;
        __syncthreads();
    }
    int myc = cnt[t];
    int excl = pos[t] - myc;
    if (myc > 0) {
        int g = atomicAdd(&gcur[t], myc);
        runb[t] = g - excl;   // final addr for LDS slot i of bucket t = runb[t] + i
    }
    __syncthreads();
    cnt[t] = excl;            // scatter cursor
    __syncthreads();

#pragma unroll
    for (int j = 0; j < 8; ++j) {
        int idx = base + ((j << 8) + t) * 4;
        int rr[4];
        if (idx + 3 < E) {
            int4 r4 = nt_load_i4(rowi + idx);
            rr[0] = r4.x; rr[1] = r4.y; rr[2] = r4.z; rr[3] = r4.w;
        } else {
#pragma unroll
            for (int u = 0; u < 4; ++u) {
                int i2 = idx + u;
                rr[u] = (i2 < E) ? rowi[i2] : 0;
            }
        }
#pragma unroll
        for (int u = 0; u < 4; ++u) {
            int c = cbuf[j * 4 + u];
            if (c >= 0) {
                int b = c >> NPB_SHIFT;
                int lp = atomicAdd(&cnt[b], 1);
                stage[lp] = (rr[u] << NPB_SHIFT) | (c & (NPB - 1));
                sbkt[lp] = (unsigned char)b;
            }
        }
    }
    __syncthreads();
    // bucket-sorted, lane-consecutive write-out
    for (int i = t; i < nval; i += 256)
        nt_store_i(stage[i], &ebin[runb[sbkt[i]] + i]);
}

// ---------------- per-node degree from binned edges (LDS counting, split-K) ----------------
__global__ __launch_bounds__(256) void degpart_kernel(const int* __restrict__ bstart,
        const int* __restrict__ ebin, int* __restrict__ degp, int K) {
    __shared__ int cnt[NPB];
    int t = threadIdx.x;
    int bid = blockIdx.x;
    int b = bid / K, slice = bid - b * K;
    cnt[t] = 0; cnt[t + 256] = 0;
    __syncthreads();
    int s = bstart[b], e = bstart[b + 1];
    int per = (e - s + K - 1) / K;
    int s0 = s + slice * per;
    int e0 = s0 + per; if (e0 > e) e0 = e;
    for (int i = s0 + t; i < e0; i += 1024) {
        int w[4];
#pragma unroll
        for (int u = 0; u < 4; ++u) {
            int idx = i + u * 256;
            w[u] = (idx < e0) ? nt_load_i(&ebin[idx]) : -1;
        }
#pragma unroll
        for (int u = 0; u < 4; ++u)
            if (w[u] >= 0) atomicAdd(&cnt[w[u] & (NPB - 1)], 1);
    }
    __syncthreads();
    int* dp = degp + (size_t)bid * NPB;
    nt_store_i(cnt[t], &dp[t]);
    nt_store_i(cnt[t + 256], &dp[t + 256]);
}

// ---------------- combine degree partials -> dinv ----------------
__global__ void dinv_kernel(const int* __restrict__ degp, float* __restrict__ dinv,
        int N, int K) {
    int i = blockIdx.x * blockDim.x + threadIdx.x;
    if (i >= N) return;
    int b = i >> NPB_SHIFT, n = i & (NPB - 1);
    int d = 0;
    for (int sl = 0; sl < K; ++sl)
        d += degp[(size_t)(b * K + sl) * NPB + n];
    dinv[i] = rsqrtf((float)(d + 1));  // +1 self loop
}

// ---------------- layer-1 GEMM: hs{A,B}[r][f] = dinv[r] * sum_k x[r,k]*W1[k,f] ----------------
__global__ __launch_bounds__(256) void gemm1_kernel(
    const float* __restrict__ x, const float* __restrict__ W1,
    const float* __restrict__ dinv, float* __restrict__ hsA,
    float* __restrict__ hsB, int N) {
    __shared__ __align__(16) float wsT[F1][XPAD];   // wsT[f][k] = W1[k][f]
    __shared__ __align__(16) float xs[16][XPAD];
    int t = threadIdx.x;
    for (int i = t; i < N_FEAT * F1; i += 256) {
        int k = i >> 4, f = i & 15;
        wsT[f][k] = W1[i];
    }
    int row0 = blockIdx.x * 16;
    for (int i = t; i < 16 * (N_FEAT / 4); i += 256) {
        int r = i >> 5, k4 = i & 31;
        int row = row0 + r;
        float4 v = (row < N) ? nt_load_f4((const float4*)(x + (size_t)row * N_FEAT) + k4)
                             : make_float4(0.f, 0.f, 0.f, 0.f);
        *(float4*)&xs[r][k4 * 4] = v;
    }
    __syncthreads();
    int rr = t >> 4, f = t & 15;
    int row = row0 + rr;
    if (row >= N) return;
    float acc = 0.f;
#pragma unroll
    for (int k4 = 0; k4 < 32; ++k4) {
        float4 xv = *(const float4*)&xs[rr][k4 * 4];
        float4 wv = *(const float4*)&wsT[f][k4 * 4];
        acc += xv.x * wv.x + xv.y * wv.y + xv.z * wv.z + xv.w * wv.w;
    }
    float v = acc * dinv[row];
    if (f < FH) hsA[(size_t)row * FH + f] = v;
    else        hsB[(size_t)row * FH + (f - FH)] = v;
}

// ------- layer-1 aggregate, one feature-half, split-K slices of each bucket -------
// One edge per lane, 4-deep unroll for MLP. hsH is 3.2 MB -> per-XCD L2-resident;
// all streaming accesses are nontemporal to protect that residency.
__global__ __launch_bounds__(512) void agg1_part_kernel(const int* __restrict__ bstart,
        const int* __restrict__ ebin, const float* __restrict__ hsH,
        float* __restrict__ partH, int K) {
    __shared__ float acc[NPB * APAD];
    int t = threadIdx.x;
    int bid = blockIdx.x;
    int b = bid / K, slice = bid - b * K;
    for (int i = t; i < NPB * APAD; i += 512) acc[i] = 0.f;
    __syncthreads();
    int s = bstart[b], e = bstart[b + 1];
    int per = (e - s + K - 1) / K;
    int s0 = s + slice * per;
    int e0 = s0 + per; if (e0 > e) e0 = e;
    const float4* h4 = (const float4*)hsH;
    for (int i = s0 + t; i < e0; i += 2048) {
        int w[4]; float4 va[4], vb[4];
#pragma unroll
        for (int u = 0; u < 4; ++u) {
            int idx = i + u * 512;
            w[u] = (idx < e0) ? nt_load_i(&ebin[idx]) : -1;
        }
#pragma unroll
        for (int u = 0; u < 4; ++u) {
            if (w[u] >= 0) {
                size_t r = (size_t)(w[u] >> NPB_SHIFT) * 2;
                va[u] = h4[r]; vb[u] = h4[r + 1];
            }
        }
#pragma unroll
        for (int u = 0; u < 4; ++u) {
            if (w[u] >= 0) {
                float* a = &acc[(w[u] & (NPB - 1)) * APAD];
                atomicAdd(a + 0, va[u].x); atomicAdd(a + 1, va[u].y);
                atomicAdd(a + 2, va[u].z); atomicAdd(a + 3, va[u].w);
                atomicAdd(a + 4, vb[u].x); atomicAdd(a + 5, vb[u].y);
                atomicAdd(a + 6, vb[u].z); atomicAdd(a + 7, vb[u].w);
            }
        }
    }
    __syncthreads();
    // flush partial: [node][2 float4], contiguous per block
    float4* p4 = (float4*)(partH + (size_t)bid * (NPB * FH));
    for (int i = t; i < NPB * FH / 4; i += 512) {
        int n = i >> 1, h = i & 1;
        float* a = &acc[n * APAD + h * 4];
        nt_store_f4(a[0], a[1], a[2], a[3], &p4[i]);
    }
}

// ------- layer-1 combine partials + self + bias + relu + W2 -> hs2 (2 lanes/node) -------
__global__ __launch_bounds__(256) void fuse1_kernel(const float* __restrict__ partA,
        const float* __restrict__ partB, const float* __restrict__ hsA,
        const float* __restrict__ hsB, const float* __restrict__ dinv,
        const float* __restrict__ b1, const float* __restrict__ W2,
        float* __restrict__ hs2, int N, int K) {
    int tid = blockIdx.x * 256 + threadIdx.x;
    int g = tid >> 1;
    int h = tid & 1;      // feature half
    if (g >= N) return;
    int b = g >> NPB_SHIFT, n = g & (NPB - 1);
    const float4* h4 = (const float4*)(h ? hsB : hsA);
    const float4* p4 = (const float4*)(h ? partB : partA);
    float4 a0 = h4[(size_t)g * 2 + 0];   // self loop
    float4 a1 = h4[(size_t)g * 2 + 1];
    for (int sl = 0; sl < K; ++sl) {
        const float4* pp = p4 + ((size_t)(b * K + sl)) * (NPB * 2) + n * 2;
        float4 q0 = nt_load_f4(pp);
        float4 q1 = nt_load_f4(pp + 1);
        a0.x += q0.x; a0.y += q0.y; a0.z += q0.z; a0.w += q0.w;
        a1.x += q1.x; a1.y += q1.y; a1.z += q1.z; a1.w += q1.w;
    }
    float di = dinv[g];
    int f0 = h * FH;
    float vv[8] = {a0.x, a0.y, a0.z, a0.w, a1.x, a1.y, a1.z, a1.w};
    float h0 = 0.f, h1 = 0.f;
#pragma unroll
    for (int u = 0; u < 8; ++u) {
        float o = fmaxf(di * vv[u] + b1[f0 + u], 0.f);
        h0 += o * W2[(f0 + u) * F2 + 0];
        h1 += o * W2[(f0 + u) * F2 + 1];
    }
    h0 += __shfl_xor(h0, 1);
    h1 += __shfl_xor(h1, 1);
    if (h == 0) *(float2*)&hs2[(size_t)g * 2] = make_float2(di * h0, di * h1);
}

// ------- layer-2 aggregate, split-K (hs2 = 800 KB, L2-resident) -------
__global__ __launch_bounds__(256) void agg2_part_kernel(const int* __restrict__ bstart,
        const int* __restrict__ ebin, const float* __restrict__ hs2,
        float* __restrict__ part2, int K) {
    __shared__ float acc[NPB * 3];
    int t = threadIdx.x;
    int bid = blockIdx.x;
    int b = bid / K, slice = bid - b * K;
    for (int i = t; i < NPB * 3; i += 256) acc[i] = 0.f;
    __syncthreads();
    int s = bstart[b], e = bstart[b + 1];
    int per = (e - s + K - 1) / K;
    int s0 = s + slice * per;
    int e0 = s0 + per; if (e0 > e) e0 = e;
    for (int i = s0 + t; i < e0; i += 1024) {
        int w[4];
#pragma unroll
        for (int u = 0; u < 4; ++u) {
            int idx = i + u * 256;
            w[u] = (idx < e0) ? nt_load_i(&ebin[idx]) : -1;
        }
#pragma unroll
        for (int u = 0; u < 4; ++u) {
            if (w[u] >= 0) {
                float2 hv = *(const float2*)&hs2[(size_t)(w[u] >> NPB_SHIFT) * 2];
                int cl = w[u] & (NPB - 1);
                atomicAdd(&acc[cl * 3 + 0], hv.x);
                atomicAdd(&acc[cl * 3 + 1], hv.y);
            }
        }
    }
    __syncthreads();
    float2* p2 = (float2*)(part2 + (size_t)bid * (NPB * F2));
    for (int i = t; i < NPB; i += 256)
        nt_store_f2(acc[i * 3 + 0], acc[i * 3 + 1], &p2[i]);
}

// ------- layer-2 combine + finalize -------
__global__ void fuse2_kernel(const float* __restrict__ part2,
        const float* __restrict__ hs2, const float* __restrict__ dinv,
        const float* __restrict__ b2, float* __restrict__ out, int N, int K) {
    int gid = blockIdx.x * blockDim.x + threadIdx.x;
    if (gid >= N * F2) return;
    int g = gid >> 1, j = gid & 1;
    int b = g >> NPB_SHIFT, n = g & (NPB - 1);
    float acc = 0.f;
    size_t rbase = ((size_t)b * K * NPB + n) * 2 + j;
    for (int s = 0; s < K; ++s)
        acc += nt_load_f(&part2[rbase + (size_t)s * NPB * 2]);
    out[gid] = dinv[g] * (acc + hs2[gid]) + b2[j];
}

extern "C" void kernel_launch(void* const* d_in, const int* in_sizes, int n_in,
                              void* d_out, int out_size, void* d_ws, size_t ws_size,
                              hipStream_t stream) {
    const float* x  = (const float*)d_in[0];
    const int*   ei = (const int*)d_in[1];
    const float* W1 = (const float*)d_in[2];
    const float* b1 = (const float*)d_in[3];
    const float* W2 = (const float*)d_in[4];
    const float* b2 = (const float*)d_in[5];
    int N = in_sizes[0] / N_FEAT;
    int E = in_sizes[1] / 2;
    const int* rowi = ei;        // edge_index[0] = src
    const int* coli = ei + E;    // edge_index[1] = dst
    float* out = (float*)d_out;

    int nbuck = (N + NPB - 1) >> NPB_SHIFT;   // 196 for N=100000 (<= BMAX)

    // workspace layout (4B units)
    size_t NP = ((size_t)N + 1023) & ~(size_t)1023;
    size_t EP = ((size_t)E + 1023) & ~(size_t)1023;
    int*   wsI    = (int*)d_ws;
    float* dinv   = (float*)wsI;                  // NP
    int*   bcnt   = wsI + NP;                     // 512
    int*   bstart = wsI + NP + 512;               // 512
    int*   gcur   = wsI + NP + 1024;              // 512
    float* hsA    = (float*)(wsI + NP + 2048);    // 8*NP
    float* hsB    = hsA + 8 * NP;                 // 8*NP
    float* hs2    = hsB + 8 * NP;                 // 2*NP
    int*   ebin   = (int*)(hs2 + 2 * NP);         // EP
    int*   degp   = ebin + EP;                    // K*nbuck*NPB
    size_t base   = NP + 2048 + 18 * NP + EP;     // 4B units used so far

    // pick largest K (<=4) whose partial buffers fit the workspace
    int K = 4;
    while (K > 1) {
        size_t need = base + (size_t)K * nbuck * NPB * (1 + F1 + F2);
        if (need * 4 <= ws_size) break;
        K >>= 1;
    }
    float* partA = (float*)(degp + (size_t)K * nbuck * NPB);
    float* partB = partA + (size_t)K * nbuck * NPB * FH;
    float* part2 = partB + (size_t)K * nbuck * NPB * FH;

    hipMemsetAsync(bcnt, 0, BMAX * sizeof(int), stream);

    hist_kernel<<<HBLK, 256, 0, stream>>>(coli, E, bcnt);
    bscan_kernel<<<1, BMAX, 0, stream>>>(bcnt, bstart, gcur, E, nbuck);
    bin_kernel<<<(E + CHUNK - 1) / CHUNK, 256, 0, stream>>>(rowi, coli, gcur, ebin, E);
    degpart_kernel<<<nbuck * K, 256, 0, stream>>>(bstart, ebin, degp, K);
    dinv_kernel<<<(N + 255) / 256, 256, 0, stream>>>(degp, dinv, N, K);
    gemm1_kernel<<<(N + 15) / 16, 256, 0, stream>>>(x, W1, dinv, hsA, hsB, N);

    // two sequential passes, each with a 3.2 MB (L2-resident) gather working set
    agg1_part_kernel<<<nbuck * K, 512, 0, stream>>>(bstart, ebin, hsA, partA, K);
    agg1_part_kernel<<<nbuck * K, 512, 0, stream>>>(bstart, ebin, hsB, partB, K);
    fuse1_kernel<<<(N * 2 + 255) / 256, 256, 0, stream>>>(
        partA, partB, hsA, hsB, dinv, b1, W2, hs2, N, K);

    agg2_part_kernel<<<nbuck * K, 256, 0, stream>>>(bstart, ebin, hs2, part2, K);
    fuse2_kernel<<<(N * 2 + 255) / 256, 256, 0, stream>>>(part2, hs2, dinv, b2, out, N, K);
}

// Round 7
// 493.814 us; speedup vs baseline: 1.4745x; 1.1539x over previous
//
#include <hip/hip_runtime.h>

#define N_FEAT 128
#define F1 16
#define F2 2
#define XPAD 132
#define NPB 512          // nodes per bucket (power of two)
#define NPB_SHIFT 9
#define BMAX 256         // max buckets -> supports N <= 131072
#define CHUNK 8192       // edges per binning block
#define HBLK 1024        // blocks for histogram kernel
#define K2 4             // degree-count slices per bucket

// ---- nontemporal helpers (builtin requires native/ext_vector types) ----
typedef int ev_i4 __attribute__((ext_vector_type(4)));

__device__ __forceinline__ int4 nt_load_i4(const void* p) {
    ev_i4 v = __builtin_nontemporal_load((const ev_i4*)p);
    return make_int4(v.x, v.y, v.z, v.w);
}
__device__ __forceinline__ int nt_load_i(const int* p) {
    return __builtin_nontemporal_load(p);
}
__device__ __forceinline__ void nt_store_i(int v, int* p) {
    __builtin_nontemporal_store(v, p);
}
__device__ __forceinline__ float nt_load_f(const float* p) {
    return __builtin_nontemporal_load(p);
}

// ---------------- bucket histogram only (NO per-node atomics) ----------------
__global__ __launch_bounds__(256) void hist_kernel(const int* __restrict__ col, int E,
        int* __restrict__ bcnt) {
    __shared__ int hist[BMAX];
    int t = threadIdx.x;
    hist[t] = 0;
    __syncthreads();
    int nq = (E + 3) >> 2;
    for (int q = blockIdx.x * 256 + t; q < nq; q += HBLK * 256) {
        int e0 = q * 4;
        if (e0 + 3 < E) {
            int4 c = nt_load_i4(col + e0);
            atomicAdd(&hist[c.x >> NPB_SHIFT], 1);
            atomicAdd(&hist[c.y >> NPB_SHIFT], 1);
            atomicAdd(&hist[c.z >> NPB_SHIFT], 1);
            atomicAdd(&hist[c.w >> NPB_SHIFT], 1);
        } else {
            for (int e = e0; e < E; ++e) atomicAdd(&hist[col[e] >> NPB_SHIFT], 1);
        }
    }
    __syncthreads();
    if (hist[t]) atomicAdd(&bcnt[t], hist[t]);
}

// ---------------- exclusive scan of bucket counts (single block) ----------------
__global__ __launch_bounds__(256) void bscan_kernel(const int* __restrict__ bcnt,
        int* __restrict__ bstart, int* __restrict__ gcur, int E, int nbuck) {
    __shared__ int s[BMAX];
    int t = threadIdx.x;
    int v = (t < nbuck) ? bcnt[t] : 0;
    s[t] = v;
    __syncthreads();
    for (int off = 1; off < BMAX; off <<= 1) {
        int a = (t >= off) ? s[t - off] : 0;
        __syncthreads();
        s[t] += a;
        __syncthreads();
    }
    int excl = s[t] - v;
    if (t < nbuck) { bstart[t] = excl; gcur[t] = excl; }
    if (t == 0) bstart[nbuck] = E;
}

// ---------------- bin edges into buckets, LDS-staged for coalesced write-out ----------------
// outputs: esrc[p] = src, edst[p] = dst, grouped by bucket = dst >> NPB_SHIFT
__global__ __launch_bounds__(256) void bin_kernel(const int* __restrict__ rowi,
        const int* __restrict__ coli, int* __restrict__ gcur,
        int* __restrict__ esrc, int* __restrict__ edst, int E) {
    __shared__ int stage[CHUNK];
    __shared__ unsigned char sbkt[CHUNK];
    __shared__ int cnt[BMAX];
    __shared__ int pos[BMAX];
    __shared__ int runb[BMAX];
    int t = threadIdx.x;
    int base = blockIdx.x * CHUNK;
    int nval = E - base; if (nval > CHUNK) nval = CHUNK;
    cnt[t] = 0;
    __syncthreads();

    int cbuf[32];
#pragma unroll
    for (int j = 0; j < 8; ++j) {
        int idx = base + ((j << 8) + t) * 4;
        if (idx + 3 < E) {
            int4 c4 = nt_load_i4(coli + idx);
            cbuf[j * 4 + 0] = c4.x; cbuf[j * 4 + 1] = c4.y;
            cbuf[j * 4 + 2] = c4.z; cbuf[j * 4 + 3] = c4.w;
        } else {
#pragma unroll
            for (int u = 0; u < 4; ++u) {
                int i2 = idx + u;
                cbuf[j * 4 + u] = (i2 < E) ? coli[i2] : -1;
            }
        }
    }
#pragma unroll
    for (int k = 0; k < 32; ++k)
        if (cbuf[k] >= 0) atomicAdd(&cnt[cbuf[k] >> NPB_SHIFT], 1);
    __syncthreads();

    // inclusive scan of cnt into pos
    pos[t] = cnt[t];
    __syncthreads();
    for (int off = 1; off < BMAX; off <<= 1) {
        int a = (t >= off) ? pos[t - off] : 0;
        __syncthreads();
        pos[t] += a;
        __syncthreads();
    }
    int myc = cnt[t];
    int excl = pos[t] - myc;
    if (myc > 0) {
        int g = atomicAdd(&gcur[t], myc);
        runb[t] = g - excl;   // final addr for LDS slot i of bucket t = runb[t] + i
    }
    __syncthreads();
    cnt[t] = excl;            // scatter cursor
    __syncthreads();

#pragma unroll
    for (int j = 0; j < 8; ++j) {
        int idx = base + ((j << 8) + t) * 4;
        int rr[4];
        if (idx + 3 < E) {
            int4 r4 = nt_load_i4(rowi + idx);
            rr[0] = r4.x; rr[1] = r4.y; rr[2] = r4.z; rr[3] = r4.w;
        } else {
#pragma unroll
            for (int u = 0; u < 4; ++u) {
                int i2 = idx + u;
                rr[u] = (i2 < E) ? rowi[i2] : 0;
            }
        }
#pragma unroll
        for (int u = 0; u < 4; ++u) {
            int c = cbuf[j * 4 + u];
            if (c >= 0) {
                int b = c >> NPB_SHIFT;
                int lp = atomicAdd(&cnt[b], 1);
                stage[lp] = (rr[u] << NPB_SHIFT) | (c & (NPB - 1));
                sbkt[lp] = (unsigned char)b;
            }
        }
    }
    __syncthreads();
    // bucket-sorted, lane-consecutive write-out
    for (int i = t; i < nval; i += 256) {
        int addr = runb[sbkt[i]] + i;
        int w = stage[i];
        nt_store_i(w >> NPB_SHIFT, &esrc[addr]);
        nt_store_i(((int)sbkt[i] << NPB_SHIFT) | (w & (NPB - 1)), &edst[addr]);
    }
}

// ---------------- per-node degree from binned edges (LDS counting, split-K) ----------------
__global__ __launch_bounds__(256) void degpart_kernel(const int* __restrict__ bstart,
        const int* __restrict__ edst, int* __restrict__ degp) {
    __shared__ int cnt[NPB];
    int t = threadIdx.x;
    int bid = blockIdx.x;
    int b = bid / K2, slice = bid - b * K2;
    cnt[t] = 0; cnt[t + 256] = 0;
    __syncthreads();
    int s = bstart[b], e = bstart[b + 1];
    int per = (e - s + K2 - 1) / K2;
    int s0 = s + slice * per;
    int e0 = s0 + per; if (e0 > e) e0 = e;
    for (int i = s0 + t; i < e0; i += 1024) {
        int w[4];
#pragma unroll
        for (int u = 0; u < 4; ++u) {
            int idx = i + u * 256;
            w[u] = (idx < e0) ? nt_load_i(&edst[idx]) : -1;
        }
#pragma unroll
        for (int u = 0; u < 4; ++u)
            if (w[u] >= 0) atomicAdd(&cnt[w[u] & (NPB - 1)], 1);
    }
    __syncthreads();
    int* dp = degp + (size_t)bid * NPB;
    nt_store_i(cnt[t], &dp[t]);
    nt_store_i(cnt[t + 256], &dp[t + 256]);
}

// ---------------- combine degree partials -> dinv ----------------
__global__ void dinv_kernel(const int* __restrict__ degp, float* __restrict__ dinv, int N) {
    int i = blockIdx.x * blockDim.x + threadIdx.x;
    if (i >= N) return;
    int b = i >> NPB_SHIFT, n = i & (NPB - 1);
    int d = 0;
    for (int sl = 0; sl < K2; ++sl)
        d += degp[(size_t)(b * K2 + sl) * NPB + n];
    dinv[i] = rsqrtf((float)(d + 1));  // +1 self loop
}

// ---------------- layer-1 GEMM: hs[r][f] = dinv[r] * sum_k x[r,k]*W1[k,f] ----------------
__global__ __launch_bounds__(256) void gemm1_kernel(
    const float* __restrict__ x, const float* __restrict__ W1,
    const float* __restrict__ dinv, float* __restrict__ hs, int N) {
    __shared__ __align__(16) float wsT[F1][XPAD];   // wsT[f][k] = W1[k][f]
    __shared__ __align__(16) float xs[16][XPAD];
    int t = threadIdx.x;
    for (int i = t; i < N_FEAT * F1; i += 256) {
        int k = i >> 4, f = i & 15;
        wsT[f][k] = W1[i];
    }
    int row0 = blockIdx.x * 16;
    for (int i = t; i < 16 * (N_FEAT / 4); i += 256) {
        int r = i >> 5, k4 = i & 31;
        int row = row0 + r;
        float4 v;
        if (row < N) {
            const float* px = x + (size_t)row * N_FEAT + k4 * 4;
            v = make_float4(nt_load_f(px), nt_load_f(px + 1), nt_load_f(px + 2),
                            nt_load_f(px + 3));
        } else {
            v = make_float4(0.f, 0.f, 0.f, 0.f);
        }
        *(float4*)&xs[r][k4 * 4] = v;
    }
    __syncthreads();
    int rr = t >> 4, f = t & 15;
    int row = row0 + rr;
    if (row >= N) return;
    float acc = 0.f;
#pragma unroll
    for (int k4 = 0; k4 < 32; ++k4) {
        float4 xv = *(const float4*)&xs[rr][k4 * 4];
        float4 wv = *(const float4*)&wsT[f][k4 * 4];
        acc += xv.x * wv.x + xv.y * wv.y + xv.z * wv.z + xv.w * wv.w;
    }
    hs[(size_t)row * F1 + f] = acc * dinv[row];
}

// ------- layer-1 scatter: bucket-ordered edges, 16 lanes per edge -------
// dst locality (512-node window) keeps acc1 lines hot at the atomic unit.
__global__ __launch_bounds__(256) void scat1_kernel(const int* __restrict__ esrc,
        const int* __restrict__ edst, const float* __restrict__ hs,
        float* __restrict__ acc1, long long total) {
    long long gid = (long long)blockIdx.x * 256 + threadIdx.x;
    if (gid >= total) return;
    int e = (int)(gid >> 4), f = (int)(gid & 15);
    int s = esrc[e];
    int d = edst[e];
    atomicAdd(&acc1[(size_t)d * F1 + f], hs[(size_t)s * F1 + f]);
}

// ------- layer-1 finalize: acc1 + self + bias + relu + W2 -> hs2 (4 lanes/node) -------
__global__ __launch_bounds__(256) void fuse1_kernel(const float* __restrict__ acc1,
        const float* __restrict__ hs, const float* __restrict__ dinv,
        const float* __restrict__ b1, const float* __restrict__ W2,
        float* __restrict__ hs2, int N) {
    int tid = blockIdx.x * 256 + threadIdx.x;
    int g = tid >> 2, q = tid & 3;
    if (g >= N) return;
    float4 a = ((const float4*)acc1)[(size_t)g * 4 + q];
    float4 sv = ((const float4*)hs)[(size_t)g * 4 + q];
    float di = dinv[g];
    int f0 = q * 4;
    float vv[4] = {a.x + sv.x, a.y + sv.y, a.z + sv.z, a.w + sv.w};
    float h0 = 0.f, h1 = 0.f;
#pragma unroll
    for (int u = 0; u < 4; ++u) {
        float o = fmaxf(di * vv[u] + b1[f0 + u], 0.f);
        h0 += o * W2[(f0 + u) * F2 + 0];
        h1 += o * W2[(f0 + u) * F2 + 1];
    }
    h0 += __shfl_xor(h0, 1); h0 += __shfl_xor(h0, 2);
    h1 += __shfl_xor(h1, 1); h1 += __shfl_xor(h1, 2);
    if (q == 0) *(float2*)&hs2[(size_t)g * 2] = make_float2(di * h0, di * h1);
}

// ------- layer-2 scatter: bucket-ordered, 2 lanes per edge -------
__global__ __launch_bounds__(256) void scat2_kernel(const int* __restrict__ esrc,
        const int* __restrict__ edst, const float* __restrict__ hs2,
        float* __restrict__ acc2, long long total) {
    long long gid = (long long)blockIdx.x * 256 + threadIdx.x;
    if (gid >= total) return;
    int e = (int)(gid >> 1), j = (int)(gid & 1);
    atomicAdd(&acc2[(size_t)edst[e] * F2 + j], hs2[(size_t)esrc[e] * F2 + j]);
}

// ------- layer-2 finalize -------
__global__ void fin2_kernel(const float* __restrict__ acc2, const float* __restrict__ hs2,
        const float* __restrict__ dinv, const float* __restrict__ b2,
        float* __restrict__ out, int N) {
    int gid = blockIdx.x * blockDim.x + threadIdx.x;
    if (gid >= N * F2) return;
    int g = gid >> 1, j = gid & 1;
    out[gid] = dinv[g] * (acc2[gid] + hs2[gid]) + b2[j];
}

extern "C" void kernel_launch(void* const* d_in, const int* in_sizes, int n_in,
                              void* d_out, int out_size, void* d_ws, size_t ws_size,
                              hipStream_t stream) {
    const float* x  = (const float*)d_in[0];
    const int*   ei = (const int*)d_in[1];
    const float* W1 = (const float*)d_in[2];
    const float* b1 = (const float*)d_in[3];
    const float* W2 = (const float*)d_in[4];
    const float* b2 = (const float*)d_in[5];
    int N = in_sizes[0] / N_FEAT;
    int E = in_sizes[1] / 2;
    const int* rowi = ei;        // edge_index[0] = src
    const int* coli = ei + E;    // edge_index[1] = dst
    float* out = (float*)d_out;

    int nbuck = (N + NPB - 1) >> NPB_SHIFT;   // 196 for N=100000 (<= BMAX)

    // workspace layout (4B units)
    size_t NP = ((size_t)N + 1023) & ~(size_t)1023;
    size_t EP = ((size_t)E + 1023) & ~(size_t)1023;
    int*   wsI    = (int*)d_ws;
    float* dinv   = (float*)wsI;                  // NP
    int*   bcnt   = wsI + NP;                     // 512
    int*   bstart = wsI + NP + 512;               // 512
    int*   gcur   = wsI + NP + 1024;              // 512 (+512 pad)
    float* hs     = (float*)(wsI + NP + 2048);    // 16*NP
    float* hs2    = hs + 16 * NP;                 // 2*NP
    float* acc1   = hs2 + 2 * NP;                 // 16*NP
    float* acc2   = acc1 + 16 * NP;               // 2*NP
    int*   esrc   = (int*)(acc2 + 2 * NP);        // EP
    int*   edst   = esrc + EP;                    // EP
    int*   degp   = edst + EP;                    // K2*nbuck*NPB

    hipMemsetAsync(bcnt, 0, BMAX * sizeof(int), stream);
    hipMemsetAsync(acc1, 0, (size_t)N * F1 * sizeof(float), stream);
    hipMemsetAsync(acc2, 0, (size_t)N * F2 * sizeof(float), stream);

    hist_kernel<<<HBLK, 256, 0, stream>>>(coli, E, bcnt);
    bscan_kernel<<<1, BMAX, 0, stream>>>(bcnt, bstart, gcur, E, nbuck);
    bin_kernel<<<(E + CHUNK - 1) / CHUNK, 256, 0, stream>>>(rowi, coli, gcur, esrc, edst, E);
    degpart_kernel<<<nbuck * K2, 256, 0, stream>>>(bstart, edst, degp);
    dinv_kernel<<<(N + 255) / 256, 256, 0, stream>>>(degp, dinv, N);
    gemm1_kernel<<<(N + 15) / 16, 256, 0, stream>>>(x, W1, dinv, hs, N);

    long long tot1 = (long long)E * F1;
    scat1_kernel<<<(int)((tot1 + 255) / 256), 256, 0, stream>>>(esrc, edst, hs, acc1, tot1);
    fuse1_kernel<<<(N * 4 + 255) / 256, 256, 0, stream>>>(acc1, hs, dinv, b1, W2, hs2, N);

    long long tot2 = (long long)E * F2;
    scat2_kernel<<<(int)((tot2 + 255) / 256), 256, 0, stream>>>(esrc, edst, hs2, acc2, tot2);
    fin2_kernel<<<(N * F2 + 255) / 256, 256, 0, stream>>>(acc2, hs2, dinv, b2, out, N);
}

// Round 8
// 359.751 us; speedup vs baseline: 2.0239x; 1.3727x over previous
//
#include <hip/hip_runtime.h>

#define N_FEAT 128
#define F1 16
#define F2 2
#define XPAD 132
#define NPB 512          // nodes per bucket (power of two)
#define NPB_SHIFT 9
#define BMAX 256         // max buckets -> supports N <= 131072
#define CHUNK 8192       // edges per binning block
#define HBLK 1024        // blocks for histogram kernel
#define K2 4             // degree-count slices per bucket

// ---- nontemporal helpers (builtin requires native/ext_vector types) ----
typedef int ev_i4 __attribute__((ext_vector_type(4)));

__device__ __forceinline__ int4 nt_load_i4(const void* p) {
    ev_i4 v = __builtin_nontemporal_load((const ev_i4*)p);
    return make_int4(v.x, v.y, v.z, v.w);
}
__device__ __forceinline__ int nt_load_i(const int* p) {
    return __builtin_nontemporal_load(p);
}
__device__ __forceinline__ void nt_store_i(int v, int* p) {
    __builtin_nontemporal_store(v, p);
}
__device__ __forceinline__ float nt_load_f(const float* p) {
    return __builtin_nontemporal_load(p);
}

// ---------------- bucket histogram only (NO per-node atomics) ----------------
__global__ __launch_bounds__(256) void hist_kernel(const int* __restrict__ col, int E,
        int* __restrict__ bcnt) {
    __shared__ int hist[BMAX];
    int t = threadIdx.x;
    hist[t] = 0;
    __syncthreads();
    int nq = (E + 3) >> 2;
    for (int q = blockIdx.x * 256 + t; q < nq; q += HBLK * 256) {
        int e0 = q * 4;
        if (e0 + 3 < E) {
            int4 c = nt_load_i4(col + e0);
            atomicAdd(&hist[c.x >> NPB_SHIFT], 1);
            atomicAdd(&hist[c.y >> NPB_SHIFT], 1);
            atomicAdd(&hist[c.z >> NPB_SHIFT], 1);
            atomicAdd(&hist[c.w >> NPB_SHIFT], 1);
        } else {
            for (int e = e0; e < E; ++e) atomicAdd(&hist[col[e] >> NPB_SHIFT], 1);
        }
    }
    __syncthreads();
    if (hist[t]) atomicAdd(&bcnt[t], hist[t]);
}

// ---------------- exclusive scan of bucket counts (single block) ----------------
__global__ __launch_bounds__(256) void bscan_kernel(const int* __restrict__ bcnt,
        int* __restrict__ bstart, int* __restrict__ gcur, int E, int nbuck) {
    __shared__ int s[BMAX];
    int t = threadIdx.x;
    int v = (t < nbuck) ? bcnt[t] : 0;
    s[t] = v;
    __syncthreads();
    for (int off = 1; off < BMAX; off <<= 1) {
        int a = (t >= off) ? s[t - off] : 0;
        __syncthreads();
        s[t] += a;
        __syncthreads();
    }
    int excl = s[t] - v;
    if (t < nbuck) { bstart[t] = excl; gcur[t] = excl; }
    if (t == 0) bstart[nbuck] = E;
}

// ---------------- bin edges into buckets, LDS-staged for coalesced write-out ----------------
// ebin word = (src << NPB_SHIFT) | (dst & (NPB-1)), grouped by bucket = dst >> NPB_SHIFT
__global__ __launch_bounds__(256) void bin_kernel(const int* __restrict__ rowi,
        const int* __restrict__ coli, int* __restrict__ gcur,
        int* __restrict__ ebin, int E) {
    __shared__ int stage[CHUNK];
    __shared__ unsigned char sbkt[CHUNK];
    __shared__ int cnt[BMAX];
    __shared__ int pos[BMAX];
    __shared__ int runb[BMAX];
    int t = threadIdx.x;
    int base = blockIdx.x * CHUNK;
    int nval = E - base; if (nval > CHUNK) nval = CHUNK;
    cnt[t] = 0;
    __syncthreads();

    int cbuf[32];
#pragma unroll
    for (int j = 0; j < 8; ++j) {
        int idx = base + ((j << 8) + t) * 4;
        if (idx + 3 < E) {
            int4 c4 = nt_load_i4(coli + idx);
            cbuf[j * 4 + 0] = c4.x; cbuf[j * 4 + 1] = c4.y;
            cbuf[j * 4 + 2] = c4.z; cbuf[j * 4 + 3] = c4.w;
        } else {
#pragma unroll
            for (int u = 0; u < 4; ++u) {
                int i2 = idx + u;
                cbuf[j * 4 + u] = (i2 < E) ? coli[i2] : -1;
            }
        }
    }
#pragma unroll
    for (int k = 0; k < 32; ++k)
        if (cbuf[k] >= 0) atomicAdd(&cnt[cbuf[k] >> NPB_SHIFT], 1);
    __syncthreads();

    // inclusive scan of cnt into pos
    pos[t] = cnt[t];
    __syncthreads();
    for (int off = 1; off < BMAX; off <<= 1) {
        int a = (t >= off) ? pos[t - off] : 0;
        __syncthreads();
        pos[t] += a;
        __syncthreads();
    }
    int myc = cnt[t];
    int excl = pos[t] - myc;
    if (myc > 0) {
        int g = atomicAdd(&gcur[t], myc);
        runb[t] = g - excl;   // final addr for LDS slot i of bucket t = runb[t] + i
    }
    __syncthreads();
    cnt[t] = excl;            // scatter cursor
    __syncthreads();

#pragma unroll
    for (int j = 0; j < 8; ++j) {
        int idx = base + ((j << 8) + t) * 4;
        int rr[4];
        if (idx + 3 < E) {
            int4 r4 = nt_load_i4(rowi + idx);
            rr[0] = r4.x; rr[1] = r4.y; rr[2] = r4.z; rr[3] = r4.w;
        } else {
#pragma unroll
            for (int u = 0; u < 4; ++u) {
                int i2 = idx + u;
                rr[u] = (i2 < E) ? rowi[i2] : 0;
            }
        }
#pragma unroll
        for (int u = 0; u < 4; ++u) {
            int c = cbuf[j * 4 + u];
            if (c >= 0) {
                int b = c >> NPB_SHIFT;
                int lp = atomicAdd(&cnt[b], 1);
                stage[lp] = (rr[u] << NPB_SHIFT) | (c & (NPB - 1));
                sbkt[lp] = (unsigned char)b;
            }
        }
    }
    __syncthreads();
    // bucket-sorted, lane-consecutive write-out
    for (int i = t; i < nval; i += 256)
        nt_store_i(stage[i], &ebin[runb[sbkt[i]] + i]);
}

// ---------------- per-node degree from binned edges (LDS counting, split-K) ----------------
__global__ __launch_bounds__(256) void degpart_kernel(const int* __restrict__ bstart,
        const int* __restrict__ ebin, int* __restrict__ degp) {
    __shared__ int cnt[NPB];
    int t = threadIdx.x;
    int bid = blockIdx.x;
    int b = bid / K2, slice = bid - b * K2;
    cnt[t] = 0; cnt[t + 256] = 0;
    __syncthreads();
    int s = bstart[b], e = bstart[b + 1];
    int per = (e - s + K2 - 1) / K2;
    int s0 = s + slice * per;
    int e0 = s0 + per; if (e0 > e) e0 = e;
    for (int i = s0 + t; i < e0; i += 1024) {
        int w[4];
#pragma unroll
        for (int u = 0; u < 4; ++u) {
            int idx = i + u * 256;
            w[u] = (idx < e0) ? nt_load_i(&ebin[idx]) : -1;
        }
#pragma unroll
        for (int u = 0; u < 4; ++u)
            if (w[u] >= 0) atomicAdd(&cnt[w[u] & (NPB - 1)], 1);
    }
    __syncthreads();
    int* dp = degp + (size_t)bid * NPB;
    nt_store_i(cnt[t], &dp[t]);
    nt_store_i(cnt[t + 256], &dp[t + 256]);
}

// ------- per-bucket: sum degree slices, LDS scan -> CSR row_start, dinv -------
__global__ __launch_bounds__(256) void rowscan_kernel(const int* __restrict__ bstart,
        const int* __restrict__ degp, int* __restrict__ rstart,
        float* __restrict__ dinv, int N, int E) {
    __shared__ int sd[NPB];
    int b = blockIdx.x, t = threadIdx.x;
    int base = b << NPB_SHIFT;
    int d0 = 0, d1 = 0;
    for (int sl = 0; sl < K2; ++sl) {
        const int* dp = degp + (size_t)(b * K2 + sl) * NPB;
        d0 += dp[t]; d1 += dp[t + 256];
    }
    sd[t] = d0; sd[t + 256] = d1;
    __syncthreads();
    // Hillis-Steele inclusive scan over 512 entries (256 threads, 2 each)
    for (int off = 1; off < NPB; off <<= 1) {
        int a0 = (t >= off) ? sd[t - off] : 0;
        int a1 = (t + 256 >= off) ? sd[t + 256 - off] : 0;
        __syncthreads();
        sd[t] += a0; sd[t + 256] += a1;
        __syncthreads();
    }
    int bs = bstart[b];
    int g0 = base + t, g1 = base + t + 256;
    if (g0 < N) { rstart[g0] = bs + sd[t] - d0;        dinv[g0] = rsqrtf((float)(d0 + 1)); }
    if (g1 < N) { rstart[g1] = bs + sd[t + 256] - d1;  dinv[g1] = rsqrtf((float)(d1 + 1)); }
    if (b == 0 && t == 0) rstart[N] = E;
}

// ------- per-bucket: scatter ebin -> csr_src using LDS int cursors -------
__global__ __launch_bounds__(512) void bin2_kernel(const int* __restrict__ bstart,
        const int* __restrict__ rstart, const int* __restrict__ ebin,
        int* __restrict__ csr, int N) {
    __shared__ int cur[NPB];
    int b = blockIdx.x, t = threadIdx.x;
    int base = b << NPB_SHIFT;
    int g = base + t;
    cur[t] = (g < N) ? rstart[g] : 0;
    __syncthreads();
    int s = bstart[b], e = bstart[b + 1];
    for (int i = s + t; i < e; i += 2048) {
        int w[4];
#pragma unroll
        for (int u = 0; u < 4; ++u) {
            int idx = i + u * 512;
            w[u] = (idx < e) ? nt_load_i(&ebin[idx]) : -1;
        }
#pragma unroll
        for (int u = 0; u < 4; ++u) {
            if (w[u] >= 0) {
                int p = atomicAdd(&cur[w[u] & (NPB - 1)], 1);
                nt_store_i(w[u] >> NPB_SHIFT, &csr[p]);
            }
        }
    }
}

// ---------------- layer-1 GEMM: hs[r][f] = dinv[r] * sum_k x[r,k]*W1[k,f] ----------------
__global__ __launch_bounds__(256) void gemm1_kernel(
    const float* __restrict__ x, const float* __restrict__ W1,
    const float* __restrict__ dinv, float* __restrict__ hs, int N) {
    __shared__ __align__(16) float wsT[F1][XPAD];   // wsT[f][k] = W1[k][f]
    __shared__ __align__(16) float xs[16][XPAD];
    int t = threadIdx.x;
    for (int i = t; i < N_FEAT * F1; i += 256) {
        int k = i >> 4, f = i & 15;
        wsT[f][k] = W1[i];
    }
    int row0 = blockIdx.x * 16;
    for (int i = t; i < 16 * (N_FEAT / 4); i += 256) {
        int r = i >> 5, k4 = i & 31;
        int row = row0 + r;
        float4 v;
        if (row < N) {
            const float* px = x + (size_t)row * N_FEAT + k4 * 4;
            v = make_float4(nt_load_f(px), nt_load_f(px + 1), nt_load_f(px + 2),
                            nt_load_f(px + 3));
        } else {
            v = make_float4(0.f, 0.f, 0.f, 0.f);
        }
        *(float4*)&xs[r][k4 * 4] = v;
    }
    __syncthreads();
    int rr = t >> 4, f = t & 15;
    int row = row0 + rr;
    if (row >= N) return;
    float acc = 0.f;
#pragma unroll
    for (int k4 = 0; k4 < 32; ++k4) {
        float4 xv = *(const float4*)&xs[rr][k4 * 4];
        float4 wv = *(const float4*)&wsT[f][k4 * 4];
        acc += xv.x * wv.x + xv.y * wv.y + xv.z * wv.z + xv.w * wv.w;
    }
    hs[(size_t)row * F1 + f] = acc * dinv[row];
}

// ------- layer-1 CSR gather + register accumulate + fused bias/relu/W2 -> hs2 -------
// 16 lanes per node (lane = feature). hs gathers are 64B-coalesced per edge.
__global__ __launch_bounds__(256) void agg1_kernel(const int* __restrict__ rstart,
        const int* __restrict__ csr, const float* __restrict__ hs,
        const float* __restrict__ dinv, const float* __restrict__ b1,
        const float* __restrict__ W2, float* __restrict__ hs2, int N) {
    int t = threadIdx.x;
    int g = blockIdx.x * 16 + (t >> 4);
    int f = t & 15;
    if (g >= N) return;
    int s = rstart[g], e = rstart[g + 1];
    float acc = hs[(size_t)g * F1 + f];   // self loop
    int k = s;
    for (; k + 4 <= e; k += 4) {
        int s0 = nt_load_i(&csr[k]);
        int s1 = nt_load_i(&csr[k + 1]);
        int s2 = nt_load_i(&csr[k + 2]);
        int s3 = nt_load_i(&csr[k + 3]);
        float v0 = hs[(size_t)s0 * F1 + f];
        float v1 = hs[(size_t)s1 * F1 + f];
        float v2 = hs[(size_t)s2 * F1 + f];
        float v3 = hs[(size_t)s3 * F1 + f];
        acc += (v0 + v1) + (v2 + v3);
    }
    for (; k < e; ++k) acc += hs[(size_t)nt_load_i(&csr[k]) * F1 + f];
    float di = dinv[g];
    float o = fmaxf(di * acc + b1[f], 0.f);
    float h0 = o * W2[f * F2 + 0];
    float h1 = o * W2[f * F2 + 1];
#pragma unroll
    for (int off = 1; off < 16; off <<= 1) {
        h0 += __shfl_xor(h0, off);
        h1 += __shfl_xor(h1, off);
    }
    if (f == 0) *(float2*)&hs2[(size_t)g * 2] = make_float2(di * h0, di * h1);
}

// ------- layer-2 CSR gather + register accumulate + fused finalize -> out -------
// 4 lanes per node: lane = (chunk c, feature j).
__global__ __launch_bounds__(256) void agg2_kernel(const int* __restrict__ rstart,
        const int* __restrict__ csr, const float* __restrict__ hs2,
        const float* __restrict__ dinv, const float* __restrict__ b2,
        float* __restrict__ out, int N) {
    int t = threadIdx.x;
    int g = blockIdx.x * 64 + (t >> 2);
    int l = t & 3;
    if (g >= N) return;
    int j = l & 1, c = l >> 1;
    int s = rstart[g], e = rstart[g + 1];
    float acc = 0.f;
    int k = s + c;
    for (; k + 6 < e; k += 8) {
        int s0 = nt_load_i(&csr[k]);
        int s1 = nt_load_i(&csr[k + 2]);
        int s2 = nt_load_i(&csr[k + 4]);
        int s3 = nt_load_i(&csr[k + 6]);
        acc += hs2[(size_t)s0 * 2 + j] + hs2[(size_t)s1 * 2 + j]
             + hs2[(size_t)s2 * 2 + j] + hs2[(size_t)s3 * 2 + j];
    }
    for (; k < e; k += 2) acc += hs2[(size_t)nt_load_i(&csr[k]) * 2 + j];
    acc += __shfl_xor(acc, 2);          // combine the two chunks per feature
    if (l < 2)
        out[(size_t)g * 2 + j] = dinv[g] * (acc + hs2[(size_t)g * 2 + j]) + b2[j];
}

extern "C" void kernel_launch(void* const* d_in, const int* in_sizes, int n_in,
                              void* d_out, int out_size, void* d_ws, size_t ws_size,
                              hipStream_t stream) {
    const float* x  = (const float*)d_in[0];
    const int*   ei = (const int*)d_in[1];
    const float* W1 = (const float*)d_in[2];
    const float* b1 = (const float*)d_in[3];
    const float* W2 = (const float*)d_in[4];
    const float* b2 = (const float*)d_in[5];
    int N = in_sizes[0] / N_FEAT;
    int E = in_sizes[1] / 2;
    const int* rowi = ei;        // edge_index[0] = src
    const int* coli = ei + E;    // edge_index[1] = dst
    float* out = (float*)d_out;

    int nbuck = (N + NPB - 1) >> NPB_SHIFT;   // 196 for N=100000 (<= BMAX)

    // workspace layout (4B units)
    size_t NP = ((size_t)N + 1023) & ~(size_t)1023;
    size_t EP = ((size_t)E + 1023) & ~(size_t)1023;
    int*   wsI    = (int*)d_ws;
    float* dinv   = (float*)wsI;                       // NP
    int*   rstart = wsI + NP;                          // NP + 1024 (N+1 used)
    int*   bcnt   = wsI + 2 * NP + 1024;               // 512
    int*   bstart = wsI + 2 * NP + 1536;               // 512
    int*   gcur   = wsI + 2 * NP + 2048;               // 512 (+512 pad)
    float* hs     = (float*)(wsI + 2 * NP + 3072);     // 16*NP
    float* hs2    = hs + 16 * NP;                      // 2*NP
    int*   ebin   = (int*)(hs2 + 2 * NP);              // EP
    int*   csr    = ebin + EP;                         // EP
    int*   degp   = csr + EP;                          // K2*nbuck*NPB

    hipMemsetAsync(bcnt, 0, BMAX * sizeof(int), stream);

    hist_kernel<<<HBLK, 256, 0, stream>>>(coli, E, bcnt);
    bscan_kernel<<<1, BMAX, 0, stream>>>(bcnt, bstart, gcur, E, nbuck);
    bin_kernel<<<(E + CHUNK - 1) / CHUNK, 256, 0, stream>>>(rowi, coli, gcur, ebin, E);
    degpart_kernel<<<nbuck * K2, 256, 0, stream>>>(bstart, ebin, degp);
    rowscan_kernel<<<nbuck, 256, 0, stream>>>(bstart, degp, rstart, dinv, N, E);
    bin2_kernel<<<nbuck, 512, 0, stream>>>(bstart, rstart, ebin, csr, N);
    gemm1_kernel<<<(N + 15) / 16, 256, 0, stream>>>(x, W1, dinv, hs, N);

    agg1_kernel<<<(N + 15) / 16, 256, 0, stream>>>(rstart, csr, hs, dinv, b1, W2, hs2, N);
    agg2_kernel<<<(N + 63) / 64, 256, 0, stream>>>(rstart, csr, hs2, dinv, b2, out, N);
}

// Round 9
// 287.747 us; speedup vs baseline: 2.5304x; 1.2502x over previous
//
#include <hip/hip_runtime.h>

#define N_FEAT 128
#define F1 16
#define F2 2
#define XPAD 132
#define NPB 512          // nodes per bucket (power of two)
#define NPB_SHIFT 9
#define BMAX 256         // max buckets -> supports N <= 131072
#define CHUNK 8192       // edges per binning block
#define HBLK 1024        // blocks for histogram kernel

// ---- nontemporal helpers (builtin requires native/ext_vector types) ----
typedef int ev_i4 __attribute__((ext_vector_type(4)));

__device__ __forceinline__ int4 nt_load_i4(const void* p) {
    ev_i4 v = __builtin_nontemporal_load((const ev_i4*)p);
    return make_int4(v.x, v.y, v.z, v.w);
}
__device__ __forceinline__ int nt_load_i(const int* p) {
    return __builtin_nontemporal_load(p);
}
__device__ __forceinline__ float nt_load_f(const float* p) {
    return __builtin_nontemporal_load(p);
}

// ---------------- bucket histogram only (NO per-node atomics) ----------------
__global__ __launch_bounds__(256) void hist_kernel(const int* __restrict__ col, int E,
        int* __restrict__ bcnt) {
    __shared__ int hist[BMAX];
    int t = threadIdx.x;
    hist[t] = 0;
    __syncthreads();
    int nq = (E + 3) >> 2;
    for (int q = blockIdx.x * 256 + t; q < nq; q += HBLK * 256) {
        int e0 = q * 4;
        if (e0 + 3 < E) {
            int4 c = nt_load_i4(col + e0);
            atomicAdd(&hist[c.x >> NPB_SHIFT], 1);
            atomicAdd(&hist[c.y >> NPB_SHIFT], 1);
            atomicAdd(&hist[c.z >> NPB_SHIFT], 1);
            atomicAdd(&hist[c.w >> NPB_SHIFT], 1);
        } else {
            for (int e = e0; e < E; ++e) atomicAdd(&hist[col[e] >> NPB_SHIFT], 1);
        }
    }
    __syncthreads();
    if (hist[t]) atomicAdd(&bcnt[t], hist[t]);
}

// ---------------- exclusive scan of bucket counts (single block) ----------------
__global__ __launch_bounds__(256) void bscan_kernel(const int* __restrict__ bcnt,
        int* __restrict__ bstart, int* __restrict__ gcur, int E, int nbuck) {
    __shared__ int s[BMAX];
    int t = threadIdx.x;
    int v = (t < nbuck) ? bcnt[t] : 0;
    s[t] = v;
    __syncthreads();
    for (int off = 1; off < BMAX; off <<= 1) {
        int a = (t >= off) ? s[t - off] : 0;
        __syncthreads();
        s[t] += a;
        __syncthreads();
    }
    int excl = s[t] - v;
    if (t < nbuck) { bstart[t] = excl; gcur[t] = excl; }
    if (t == 0) bstart[nbuck] = E;
}

// ---------------- bin edges into buckets, LDS-staged for coalesced write-out ----------------
// ebin word = (src << NPB_SHIFT) | (dst & (NPB-1)), grouped by bucket = dst >> NPB_SHIFT
__global__ __launch_bounds__(256) void bin_kernel(const int* __restrict__ rowi,
        const int* __restrict__ coli, int* __restrict__ gcur,
        int* __restrict__ ebin, int E) {
    __shared__ int stage[CHUNK];
    __shared__ unsigned char sbkt[CHUNK];
    __shared__ int cnt[BMAX];
    __shared__ int pos[BMAX];
    __shared__ int runb[BMAX];
    int t = threadIdx.x;
    int base = blockIdx.x * CHUNK;
    int nval = E - base; if (nval > CHUNK) nval = CHUNK;
    cnt[t] = 0;
    __syncthreads();

    int cbuf[32];
#pragma unroll
    for (int j = 0; j < 8; ++j) {
        int idx = base + ((j << 8) + t) * 4;
        if (idx + 3 < E) {
            int4 c4 = nt_load_i4(coli + idx);
            cbuf[j * 4 + 0] = c4.x; cbuf[j * 4 + 1] = c4.y;
            cbuf[j * 4 + 2] = c4.z; cbuf[j * 4 + 3] = c4.w;
        } else {
#pragma unroll
            for (int u = 0; u < 4; ++u) {
                int i2 = idx + u;
                cbuf[j * 4 + u] = (i2 < E) ? coli[i2] : -1;
            }
        }
    }
#pragma unroll
    for (int k = 0; k < 32; ++k)
        if (cbuf[k] >= 0) atomicAdd(&cnt[cbuf[k] >> NPB_SHIFT], 1);
    __syncthreads();

    // inclusive scan of cnt into pos
    pos[t] = cnt[t];
    __syncthreads();
    for (int off = 1; off < BMAX; off <<= 1) {
        int a = (t >= off) ? pos[t - off] : 0;
        __syncthreads();
        pos[t] += a;
        __syncthreads();
    }
    int myc = cnt[t];
    int excl = pos[t] - myc;
    if (myc > 0) {
        int g = atomicAdd(&gcur[t], myc);
        runb[t] = g - excl;   // final addr for LDS slot i of bucket t = runb[t] + i
    }
    __syncthreads();
    cnt[t] = excl;            // scatter cursor
    __syncthreads();

#pragma unroll
    for (int j = 0; j < 8; ++j) {
        int idx = base + ((j << 8) + t) * 4;
        int rr[4];
        if (idx + 3 < E) {
            int4 r4 = nt_load_i4(rowi + idx);
            rr[0] = r4.x; rr[1] = r4.y; rr[2] = r4.z; rr[3] = r4.w;
        } else {
#pragma unroll
            for (int u = 0; u < 4; ++u) {
                int i2 = idx + u;
                rr[u] = (i2 < E) ? rowi[i2] : 0;
            }
        }
#pragma unroll
        for (int u = 0; u < 4; ++u) {
            int c = cbuf[j * 4 + u];
            if (c >= 0) {
                int b = c >> NPB_SHIFT;
                int lp = atomicAdd(&cnt[b], 1);
                stage[lp] = (rr[u] << NPB_SHIFT) | (c & (NPB - 1));
                sbkt[lp] = (unsigned char)b;
            }
        }
    }
    __syncthreads();
    // bucket-sorted, lane-consecutive write-out (PLAIN stores: let L2 write-combine)
    for (int i = t; i < nval; i += 256)
        ebin[runb[sbkt[i]] + i] = stage[i];
}

// ------- per-bucket CSR build: count (LDS) -> scan -> rstart/dinv -> scatter (LDS cursors) ----
__global__ __launch_bounds__(512) void csr_kernel(const int* __restrict__ bstart,
        const int* __restrict__ ebin, int* __restrict__ rstart,
        float* __restrict__ dinv, int* __restrict__ csr, int N, int E) {
    __shared__ int cnt[NPB];
    __shared__ int scn[NPB];
    int b = blockIdx.x, t = threadIdx.x;
    cnt[t] = 0;
    __syncthreads();
    int s = bstart[b], e = bstart[b + 1];
    // pass 1: per-node degree (plain loads: keep bucket hot in L2 for pass 2)
    for (int i = s + t; i < e; i += 2048) {
        int w[4];
#pragma unroll
        for (int u = 0; u < 4; ++u) {
            int idx = i + u * 512;
            w[u] = (idx < e) ? ebin[idx] : -1;
        }
#pragma unroll
        for (int u = 0; u < 4; ++u)
            if (w[u] >= 0) atomicAdd(&cnt[w[u] & (NPB - 1)], 1);
    }
    __syncthreads();
    int d = cnt[t];
    scn[t] = d;
    __syncthreads();
    // Hillis-Steele inclusive scan over 512
    for (int off = 1; off < NPB; off <<= 1) {
        int a = (t >= off) ? scn[t - off] : 0;
        __syncthreads();
        scn[t] += a;
        __syncthreads();
    }
    int g = (b << NPB_SHIFT) + t;
    int rs = s + scn[t] - d;     // exclusive start (global)
    if (g < N) {
        rstart[g] = rs;
        dinv[g] = rsqrtf((float)(d + 1));   // +1 self loop
    }
    if (b == 0 && t == 0) rstart[N] = E;
    cnt[t] = rs;                 // reuse as scatter cursor
    __syncthreads();
    // pass 2: scatter src into csr (PLAIN stores into hot 64KB window)
    for (int i = s + t; i < e; i += 2048) {
        int w[4];
#pragma unroll
        for (int u = 0; u < 4; ++u) {
            int idx = i + u * 512;
            w[u] = (idx < e) ? ebin[idx] : -1;
        }
#pragma unroll
        for (int u = 0; u < 4; ++u) {
            if (w[u] >= 0) {
                int p = atomicAdd(&cnt[w[u] & (NPB - 1)], 1);
                csr[p] = w[u] >> NPB_SHIFT;
            }
        }
    }
}

// ---------------- layer-1 GEMM: hs[r][f] = dinv[r] * sum_k x[r,k]*W1[k,f] ----------------
__global__ __launch_bounds__(256) void gemm1_kernel(
    const float* __restrict__ x, const float* __restrict__ W1,
    const float* __restrict__ dinv, float* __restrict__ hs, int N) {
    __shared__ __align__(16) float wsT[F1][XPAD];   // wsT[f][k] = W1[k][f]
    __shared__ __align__(16) float xs[16][XPAD];
    int t = threadIdx.x;
    for (int i = t; i < N_FEAT * F1; i += 256) {
        int k = i >> 4, f = i & 15;
        wsT[f][k] = W1[i];
    }
    int row0 = blockIdx.x * 16;
    for (int i = t; i < 16 * (N_FEAT / 4); i += 256) {
        int r = i >> 5, k4 = i & 31;
        int row = row0 + r;
        float4 v;
        if (row < N) {
            const float* px = x + (size_t)row * N_FEAT + k4 * 4;
            v = make_float4(nt_load_f(px), nt_load_f(px + 1), nt_load_f(px + 2),
                            nt_load_f(px + 3));
        } else {
            v = make_float4(0.f, 0.f, 0.f, 0.f);
        }
        *(float4*)&xs[r][k4 * 4] = v;
    }
    __syncthreads();
    int rr = t >> 4, f = t & 15;
    int row = row0 + rr;
    if (row >= N) return;
    float acc = 0.f;
#pragma unroll
    for (int k4 = 0; k4 < 32; ++k4) {
        float4 xv = *(const float4*)&xs[rr][k4 * 4];
        float4 wv = *(const float4*)&wsT[f][k4 * 4];
        acc += xv.x * wv.x + xv.y * wv.y + xv.z * wv.z + xv.w * wv.w;
    }
    hs[(size_t)row * F1 + f] = acc * dinv[row];
}

// ------- layer-1 CSR gather + register accumulate + fused bias/relu/W2 -> hs2 -------
// 16 lanes per node (lane = feature). hs gathers are 64B-coalesced per edge.
__global__ __launch_bounds__(256) void agg1_kernel(const int* __restrict__ rstart,
        const int* __restrict__ csr, const float* __restrict__ hs,
        const float* __restrict__ dinv, const float* __restrict__ b1,
        const float* __restrict__ W2, float* __restrict__ hs2, int N) {
    int t = threadIdx.x;
    int g = blockIdx.x * 16 + (t >> 4);
    int f = t & 15;
    if (g >= N) return;
    int s = rstart[g], e = rstart[g + 1];
    float acc = hs[(size_t)g * F1 + f];   // self loop
    int k = s;
    for (; k + 4 <= e; k += 4) {
        int s0 = nt_load_i(&csr[k]);
        int s1 = nt_load_i(&csr[k + 1]);
        int s2 = nt_load_i(&csr[k + 2]);
        int s3 = nt_load_i(&csr[k + 3]);
        float v0 = hs[(size_t)s0 * F1 + f];
        float v1 = hs[(size_t)s1 * F1 + f];
        float v2 = hs[(size_t)s2 * F1 + f];
        float v3 = hs[(size_t)s3 * F1 + f];
        acc += (v0 + v1) + (v2 + v3);
    }
    for (; k < e; ++k) acc += hs[(size_t)nt_load_i(&csr[k]) * F1 + f];
    float di = dinv[g];
    float o = fmaxf(di * acc + b1[f], 0.f);
    float h0 = o * W2[f * F2 + 0];
    float h1 = o * W2[f * F2 + 1];
#pragma unroll
    for (int off = 1; off < 16; off <<= 1) {
        h0 += __shfl_xor(h0, off);
        h1 += __shfl_xor(h1, off);
    }
    if (f == 0) *(float2*)&hs2[(size_t)g * 2] = make_float2(di * h0, di * h1);
}

// ------- layer-2 CSR gather + register accumulate + fused finalize -> out -------
// 4 lanes per node: lane = (chunk c, feature j).
__global__ __launch_bounds__(256) void agg2_kernel(const int* __restrict__ rstart,
        const int* __restrict__ csr, const float* __restrict__ hs2,
        const float* __restrict__ dinv, const float* __restrict__ b2,
        float* __restrict__ out, int N) {
    int t = threadIdx.x;
    int g = blockIdx.x * 64 + (t >> 2);
    int l = t & 3;
    if (g >= N) return;
    int j = l & 1, c = l >> 1;
    int s = rstart[g], e = rstart[g + 1];
    float acc = 0.f;
    int k = s + c;
    for (; k + 6 < e; k += 8) {
        int s0 = nt_load_i(&csr[k]);
        int s1 = nt_load_i(&csr[k + 2]);
        int s2 = nt_load_i(&csr[k + 4]);
        int s3 = nt_load_i(&csr[k + 6]);
        acc += hs2[(size_t)s0 * 2 + j] + hs2[(size_t)s1 * 2 + j]
             + hs2[(size_t)s2 * 2 + j] + hs2[(size_t)s3 * 2 + j];
    }
    for (; k < e; k += 2) acc += hs2[(size_t)nt_load_i(&csr[k]) * 2 + j];
    acc += __shfl_xor(acc, 2);          // combine the two chunks per feature
    if (l < 2)
        out[(size_t)g * 2 + j] = dinv[g] * (acc + hs2[(size_t)g * 2 + j]) + b2[j];
}

extern "C" void kernel_launch(void* const* d_in, const int* in_sizes, int n_in,
                              void* d_out, int out_size, void* d_ws, size_t ws_size,
                              hipStream_t stream) {
    const float* x  = (const float*)d_in[0];
    const int*   ei = (const int*)d_in[1];
    const float* W1 = (const float*)d_in[2];
    const float* b1 = (const float*)d_in[3];
    const float* W2 = (const float*)d_in[4];
    const float* b2 = (const float*)d_in[5];
    int N = in_sizes[0] / N_FEAT;
    int E = in_sizes[1] / 2;
    const int* rowi = ei;        // edge_index[0] = src
    const int* coli = ei + E;    // edge_index[1] = dst
    float* out = (float*)d_out;

    int nbuck = (N + NPB - 1) >> NPB_SHIFT;   // 196 for N=100000 (<= BMAX)

    // workspace layout (4B units)
    size_t NP = ((size_t)N + 1023) & ~(size_t)1023;
    size_t EP = ((size_t)E + 1023) & ~(size_t)1023;
    int*   wsI    = (int*)d_ws;
    float* dinv   = (float*)wsI;                       // NP
    int*   rstart = wsI + NP;                          // NP + 1024 (N+1 used)
    int*   bcnt   = wsI + 2 * NP + 1024;               // 512
    int*   bstart = wsI + 2 * NP + 1536;               // 512
    int*   gcur   = wsI + 2 * NP + 2048;               // 512 (+512 pad)
    float* hs     = (float*)(wsI + 2 * NP + 3072);     // 16*NP
    float* hs2    = hs + 16 * NP;                      // 2*NP
    int*   ebin   = (int*)(hs2 + 2 * NP);              // EP
    int*   csr    = ebin + EP;                         // EP

    hipMemsetAsync(bcnt, 0, BMAX * sizeof(int), stream);

    hist_kernel<<<HBLK, 256, 0, stream>>>(coli, E, bcnt);
    bscan_kernel<<<1, BMAX, 0, stream>>>(bcnt, bstart, gcur, E, nbuck);
    bin_kernel<<<(E + CHUNK - 1) / CHUNK, 256, 0, stream>>>(rowi, coli, gcur, ebin, E);
    csr_kernel<<<nbuck, 512, 0, stream>>>(bstart, ebin, rstart, dinv, csr, N, E);
    gemm1_kernel<<<(N + 15) / 16, 256, 0, stream>>>(x, W1, dinv, hs, N);

    agg1_kernel<<<(N + 15) / 16, 256, 0, stream>>>(rstart, csr, hs, dinv, b1, W2, hs2, N);
    agg2_kernel<<<(N + 63) / 64, 256, 0, stream>>>(rstart, csr, hs2, dinv, b2, out, N);
}